// Round 12
// baseline (222.770 us; speedup 1.0000x reference)
//
#include <hip/hip_runtime.h>
#include <cstddef>

typedef short s4v __attribute__((ext_vector_type(4)));
typedef short s8v __attribute__((ext_vector_type(8)));
typedef float f4v __attribute__((ext_vector_type(4)));

__device__ __forceinline__ unsigned short f2bf(float f) {
    union { float f; unsigned u; } v; v.f = f;
    unsigned r = v.u + 0x7fff + ((v.u >> 16) & 1);
    return (unsigned short)(r >> 16);
}
__device__ __forceinline__ float bf2f(unsigned short u) {
    union { unsigned u; float f; } v; v.u = ((unsigned)u) << 16;
    return v.f;
}

// async global->LDS, 16B per lane. LDS dest is wave-uniform base + lane*16.
__device__ __forceinline__ void gl_lds16(const void* g, void* l) {
    __builtin_amdgcn_global_load_lds(
        (const __attribute__((address_space(1))) void*)g,
        (__attribute__((address_space(3))) void*)l, 16, 0, 0);
}

#define QSC   0.18033688011112043f   /* 0.125 * log2(e) */
#define EOFF  23.082320654223414f    /* 16 * log2(e) */

// ---------------------------------------------------------------------------
// Fused f32 -> bf16 conversion for x, qkv_w, proj_w (one launch).
// ---------------------------------------------------------------------------
__global__ __launch_bounds__(256) void to_bf16_all(
    const float* __restrict__ x, const float* __restrict__ qw,
    const float* __restrict__ pw, unsigned short* __restrict__ xd,
    unsigned short* __restrict__ qd, unsigned short* __restrict__ pd)
{
    int i = blockIdx.x * 256 + threadIdx.x;
    const float* s; unsigned short* d; int j;
    if (i < 786432)       { s = x;  d = xd; j = i; }
    else if (i < 1007616) { s = qw; d = qd; j = i - 786432; }
    else                  { s = pw; d = pd; j = i - 1007616; }
    float4 f0 = ((const float4*)s)[j * 2];
    float4 f1 = ((const float4*)s)[j * 2 + 1];
    uint4 pk;
    pk.x = (unsigned)f2bf(f0.x) | ((unsigned)f2bf(f0.y) << 16);
    pk.y = (unsigned)f2bf(f0.z) | ((unsigned)f2bf(f0.w) << 16);
    pk.z = (unsigned)f2bf(f1.x) | ((unsigned)f2bf(f1.y) << 16);
    pk.w = (unsigned)f2bf(f1.z) | ((unsigned)f2bf(f1.w) << 16);
    ((uint4*)d)[j] = pk;
}

// ---------------------------------------------------------------------------
// R20 qkv GEMM: 256(M)x256(N) tile, 8 waves of 64x128 (4M x 2N), acc[4][8].
// LDS traffic per FLOP -27% vs 256x128 (dupA=2/dupB=4 is the optimal split);
// triple-buffered, counted vmcnt(8) depth-2 pipeline (4 loads/wave/iter).
// 288 blocks; N-tiles of 256 divide q/k/v 768-spans exactly (bc/3).
// ---------------------------------------------------------------------------
__global__ __launch_bounds__(512, 2) void qkv_gemm_mfma(
    const unsigned short* __restrict__ A, const unsigned short* __restrict__ W,
    const float* __restrict__ bias,
    unsigned short* __restrict__ qb, unsigned short* __restrict__ kb,
    unsigned short* __restrict__ vt)
{
    __shared__ __align__(16) unsigned short As[3][256 * 32];
    __shared__ __align__(16) unsigned short Bs[3][256 * 32];
    const int t     = threadIdx.x;
    const int lin   = blockIdx.x;   // 0..287
    const int xcd   = lin & 7;
    const int sq    = lin >> 3;     // 0..35
    const int br    = (xcd << 2) + (sq & 3);   // row-tile 0..31 (256 rows)
    const int bc    = sq >> 2;                 // col-tile 0..8  (256 cols)
    const int wv    = t >> 6;       // 0..7
    const int lane  = t & 63;
    const int col16 = lane & 15;
    const int quad  = lane >> 4;
    const int w4    = lane >> 2;
    const int k8    = (lane & 3) << 3;
    const int mw    = wv >> 1;      // 0..3 : A rows mw*64..+64
    const int nw    = wv & 1;       // 0..1 : B cols nw*128..+128

    const unsigned short* Ag = A + (size_t)(br * 256 + (wv << 5) + w4) * 768 + k8;
    const unsigned short* Wg = W + (size_t)(bc * 256 + (wv << 5) + w4) * 768 + k8;
    const int wo = (wv << 5) * 32;

    f4v acc[4][8];
#pragma unroll
    for (int mt = 0; mt < 4; ++mt)
#pragma unroll
        for (int nt = 0; nt < 8; ++nt) {
            acc[mt][nt][0] = 0.f; acc[mt][nt][1] = 0.f;
            acc[mt][nt][2] = 0.f; acc[mt][nt][3] = 0.f;
        }

    // prologue: stage k-steps 0 and 1 (8 loads/wave in flight)
    gl_lds16(Ag,                 &As[0][wo]);
    gl_lds16(Ag + 16 * 768,      &As[0][wo + 16 * 32]);
    gl_lds16(Wg,                 &Bs[0][wo]);
    gl_lds16(Wg + 16 * 768,      &Bs[0][wo + 16 * 32]);
    gl_lds16(Ag + 32,            &As[1][wo]);
    gl_lds16(Ag + 32 + 16 * 768, &As[1][wo + 16 * 32]);
    gl_lds16(Wg + 32,            &Bs[1][wo]);
    gl_lds16(Wg + 32 + 16 * 768, &Bs[1][wo + 16 * 32]);

#pragma unroll
    for (int kt = 0; kt < 24; ++kt) {
        if (kt < 22) {
            const int nb = (kt + 2) % 3;
            const int ko = (kt + 2) * 32;
            gl_lds16(Ag + ko,            &As[nb][wo]);
            gl_lds16(Ag + ko + 16 * 768, &As[nb][wo + 16 * 32]);
            gl_lds16(Wg + ko,            &Bs[nb][wo]);
            gl_lds16(Wg + ko + 16 * 768, &Bs[nb][wo + 16 * 32]);
        }
        if (kt < 22)       asm volatile("s_waitcnt vmcnt(8)" ::: "memory");
        else if (kt == 22) asm volatile("s_waitcnt vmcnt(4)" ::: "memory");
        else               asm volatile("s_waitcnt vmcnt(0)" ::: "memory");
        __builtin_amdgcn_s_barrier();
        asm volatile("" ::: "memory");

        const unsigned short* Ab = As[kt % 3];
        const unsigned short* Bb = Bs[kt % 3];
        s8v a[4];
#pragma unroll
        for (int mt = 0; mt < 4; ++mt)
            a[mt] = *(const s8v*)&Ab[(mw * 64 + mt * 16 + col16) * 32 + quad * 8];
#pragma unroll
        for (int nt = 0; nt < 8; ++nt) {
            s8v b = *(const s8v*)&Bb[(nw * 128 + nt * 16 + col16) * 32 + quad * 8];
#pragma unroll
            for (int mt = 0; mt < 4; ++mt)
                acc[mt][nt] = __builtin_amdgcn_mfma_f32_16x16x32_bf16(
                    a[mt], b, acc[mt][nt], 0, 0, 0);
        }

        asm volatile("" ::: "memory");
        __builtin_amdgcn_s_barrier();
    }

    const int which = bc / 3;                       // 0:q 1:k 2:v
    const int cb    = (bc % 3) * 256 + nw * 128;    // col base within 768
    const int m0    = br * 256 + mw * 64 + quad * 4;
    if (which == 2) {
        // V transposed: [bh][d][tok], 4 consecutive toks per b64 store
#pragma unroll
        for (int nt = 0; nt < 8; ++nt) {
            int c    = cb + nt * 16 + col16;
            int head = c >> 6, d = c & 63;
            float bv = bias[1536 + c];
#pragma unroll
            for (int mt = 0; mt < 4; ++mt) {
                int mb  = m0 + mt * 16;
                int bbk = mb >> 10, tok = mb & 1023;
                uint2 pk;
                pk.x = (unsigned)f2bf(acc[mt][nt][0] + bv)
                     | ((unsigned)f2bf(acc[mt][nt][1] + bv) << 16);
                pk.y = (unsigned)f2bf(acc[mt][nt][2] + bv)
                     | ((unsigned)f2bf(acc[mt][nt][3] + bv) << 16);
                *(uint2*)&vt[((size_t)(bbk * 12 + head)) * 65536 + (size_t)d * 1024 + tok] = pk;
            }
        }
    } else {
        // q carries 0.125*log2e so downstream softmax can use exp2 directly
        const float sc = (which == 0) ? QSC : 1.0f;
        unsigned short* dst = (which == 0) ? qb : kb;
#pragma unroll
        for (int nt = 0; nt < 8; ++nt) {
            int c    = cb + nt * 16 + col16;
            int head = c >> 6, d = c & 63;
            float bv = bias[which * 768 + c];
#pragma unroll
            for (int mt = 0; mt < 4; ++mt) {
#pragma unroll
                for (int i = 0; i < 4; ++i) {
                    int m   = m0 + mt * 16 + i;
                    int bbk = m >> 10, tok = m & 1023;
                    dst[(((size_t)(bbk * 12 + head) << 10) + tok) * 64 + d] =
                        f2bf((acc[mt][nt][i] + bv) * sc);
                }
            }
        }
    }
}

// ---------------------------------------------------------------------------
// R18 proj GEMM (unchanged): 256x128, triple-buffer depth-2 counted vmcnt.
// ---------------------------------------------------------------------------
__global__ __launch_bounds__(512) void proj_gemm_mfma(
    const unsigned short* __restrict__ A, const unsigned short* __restrict__ W,
    const float* __restrict__ bias, float* __restrict__ Out)
{
    __shared__ __align__(16) unsigned short As[3][256 * 32];
    __shared__ __align__(16) unsigned short Bs[3][128 * 32];
    const int t     = threadIdx.x;
    const int lin   = blockIdx.x;   // 0..191
    const int xcd   = lin & 7;
    const int sq    = lin >> 3;     // 0..23
    const int br    = (xcd << 2) + (sq & 3);   // 0..31
    const int bc    = sq >> 2;                 // 0..5
    const int wv    = t >> 6;
    const int lane  = t & 63;
    const int col16 = lane & 15;
    const int quad  = lane >> 4;
    const int w4    = lane >> 2;
    const int k8    = (lane & 3) << 3;
    const int mw    = wv >> 1, nw = wv & 1;

    const unsigned short* Ag = A + (size_t)(br * 256 + (wv << 5) + w4) * 768 + k8;
    const unsigned short* Wg = W + (size_t)(bc * 128 + (wv << 4) + w4) * 768 + k8;
    const int woA = (wv << 5) * 32;
    const int woB = (wv << 4) * 32;

    f4v acc[4][4];
#pragma unroll
    for (int mt = 0; mt < 4; ++mt)
#pragma unroll
        for (int nt = 0; nt < 4; ++nt) {
            acc[mt][nt][0] = 0.f; acc[mt][nt][1] = 0.f;
            acc[mt][nt][2] = 0.f; acc[mt][nt][3] = 0.f;
        }

    gl_lds16(Ag,                 &As[0][woA]);
    gl_lds16(Ag + 16 * 768,      &As[0][woA + 16 * 32]);
    gl_lds16(Wg,                 &Bs[0][woB]);
    gl_lds16(Ag + 32,            &As[1][woA]);
    gl_lds16(Ag + 32 + 16 * 768, &As[1][woA + 16 * 32]);
    gl_lds16(Wg + 32,            &Bs[1][woB]);

#pragma unroll
    for (int kt = 0; kt < 24; ++kt) {
        if (kt < 22) {
            const int nb = (kt + 2) % 3;
            const int ko = (kt + 2) * 32;
            gl_lds16(Ag + ko,            &As[nb][woA]);
            gl_lds16(Ag + ko + 16 * 768, &As[nb][woA + 16 * 32]);
            gl_lds16(Wg + ko,            &Bs[nb][woB]);
        }
        if (kt < 22)       asm volatile("s_waitcnt vmcnt(6)" ::: "memory");
        else if (kt == 22) asm volatile("s_waitcnt vmcnt(3)" ::: "memory");
        else               asm volatile("s_waitcnt vmcnt(0)" ::: "memory");
        __builtin_amdgcn_s_barrier();
        asm volatile("" ::: "memory");

        const unsigned short* Ab = As[kt % 3];
        const unsigned short* Bb = Bs[kt % 3];
        s8v a[4], b[4];
#pragma unroll
        for (int mt = 0; mt < 4; ++mt)
            a[mt] = *(const s8v*)&Ab[(mw * 64 + mt * 16 + col16) * 32 + quad * 8];
#pragma unroll
        for (int nt = 0; nt < 4; ++nt)
            b[nt] = *(const s8v*)&Bb[(nw * 64 + nt * 16 + col16) * 32 + quad * 8];
#pragma unroll
        for (int mt = 0; mt < 4; ++mt)
#pragma unroll
            for (int nt = 0; nt < 4; ++nt)
                acc[mt][nt] = __builtin_amdgcn_mfma_f32_16x16x32_bf16(
                    a[mt], b[nt], acc[mt][nt], 0, 0, 0);

        asm volatile("" ::: "memory");
        __builtin_amdgcn_s_barrier();
    }

    const int m0 = br * 256 + mw * 64 + quad * 4;
#pragma unroll
    for (int nt = 0; nt < 4; ++nt) {
        int c    = bc * 128 + nw * 64 + nt * 16 + col16;
        float bv = bias[c];
#pragma unroll
        for (int mt = 0; mt < 4; ++mt) {
#pragma unroll
            for (int i = 0; i < 4; ++i) {
                int m = m0 + mt * 16 + i;
                Out[(size_t)m * 768 + c] = acc[mt][nt][i] + bv;
            }
        }
    }
}

// ---------------------------------------------------------------------------
// Bias-table precompute via MFMA (unchanged).
// ---------------------------------------------------------------------------
__global__ __launch_bounds__(256) void bias_prep_mfma(
    const unsigned short* __restrict__ Q, const float* __restrict__ Rh,
    const float* __restrict__ Rw, unsigned short* __restrict__ qhb,
    unsigned short* __restrict__ qwb)
{
    __shared__ __align__(16) char smem[36864];
    unsigned short (*Qs)[72]  = (unsigned short (*)[72])smem;
    unsigned short (*Rs)[72]  = (unsigned short (*)[72])(smem + 18432);
    unsigned short (*Wsm)[72] = (unsigned short (*)[72])(smem + 27648);
    float (*G)[66]            = (float (*)[66])smem;

    const int t    = threadIdx.x;
    const int tc8  = blockIdx.x;   // 0..7 : 128-token chunk
    const int bh   = blockIdx.y;   // 0..95
    const int tok0 = tc8 << 7;

    for (int id = t; id < 1024; id += 256) {
        int row = id >> 3, g8 = (id & 7) << 3;
        *(uint4*)&Qs[row][g8] =
            *(const uint4*)(Q + ((size_t)bh * 1024 + tok0 + row) * 64 + g8);
    }
    for (int id = t; id < 512; id += 256) {
        int row = id >> 3, g8 = (id & 7) << 3;
        unsigned short* dh = &Rs[row][g8];
        unsigned short* dw = &Wsm[row][g8];
        if (row < 63) {
            const float* sh = Rh + row * 64 + g8;
            const float* sw = Rw + row * 64 + g8;
            float4 a = *(const float4*)sh; float4 b = *(const float4*)(sh + 4);
            float4 c = *(const float4*)sw; float4 d = *(const float4*)(sw + 4);
            dh[0] = f2bf(a.x); dh[1] = f2bf(a.y); dh[2] = f2bf(a.z); dh[3] = f2bf(a.w);
            dh[4] = f2bf(b.x); dh[5] = f2bf(b.y); dh[6] = f2bf(b.z); dh[7] = f2bf(b.w);
            dw[0] = f2bf(c.x); dw[1] = f2bf(c.y); dw[2] = f2bf(c.z); dw[3] = f2bf(c.w);
            dw[4] = f2bf(d.x); dw[5] = f2bf(d.y); dw[6] = f2bf(d.z); dw[7] = f2bf(d.w);
        } else {
#pragma unroll
            for (int j = 0; j < 8; ++j) { dh[j] = 0; dw[j] = 0; }
        }
    }
    __syncthreads();

    const int wv    = t >> 6;
    const int lane  = t & 63;
    const int col16 = lane & 15;
    const int quad  = lane >> 4;
    const int r0    = wv << 5;

    s8v qa[2][2], rb[4][2], wb[4][2];
#pragma unroll
    for (int mt = 0; mt < 2; ++mt)
#pragma unroll
        for (int kc = 0; kc < 2; ++kc)
            qa[mt][kc] = *(const s8v*)&Qs[r0 + mt * 16 + col16][kc * 32 + quad * 8];
#pragma unroll
    for (int nt = 0; nt < 4; ++nt)
#pragma unroll
        for (int kc = 0; kc < 2; ++kc) {
            rb[nt][kc] = *(const s8v*)&Rs[nt * 16 + col16][kc * 32 + quad * 8];
            wb[nt][kc] = *(const s8v*)&Wsm[nt * 16 + col16][kc * 32 + quad * 8];
        }

    f4v ah[2][4], aw[2][4];
#pragma unroll
    for (int mt = 0; mt < 2; ++mt)
#pragma unroll
        for (int nt = 0; nt < 4; ++nt) {
            f4v z; z[0] = 0.f; z[1] = 0.f; z[2] = 0.f; z[3] = 0.f;
            ah[mt][nt] = z; aw[mt][nt] = z;
        }
#pragma unroll
    for (int mt = 0; mt < 2; ++mt)
#pragma unroll
        for (int nt = 0; nt < 4; ++nt) {
            ah[mt][nt] = __builtin_amdgcn_mfma_f32_16x16x32_bf16(qa[mt][0], rb[nt][0], ah[mt][nt], 0, 0, 0);
            ah[mt][nt] = __builtin_amdgcn_mfma_f32_16x16x32_bf16(qa[mt][1], rb[nt][1], ah[mt][nt], 0, 0, 0);
            aw[mt][nt] = __builtin_amdgcn_mfma_f32_16x16x32_bf16(qa[mt][0], wb[nt][0], aw[mt][nt], 0, 0, 0);
            aw[mt][nt] = __builtin_amdgcn_mfma_f32_16x16x32_bf16(qa[mt][1], wb[nt][1], aw[mt][nt], 0, 0, 0);
        }
    __syncthreads();

    // ---- G_h ----
#pragma unroll
    for (int mt = 0; mt < 2; ++mt)
#pragma unroll
        for (int nt = 0; nt < 4; ++nt)
#pragma unroll
            for (int i = 0; i < 4; ++i)
                G[r0 + mt * 16 + quad * 4 + i][nt * 16 + col16] = ah[mt][nt][i];
    __syncthreads();
    for (int id = t; id < 2048; id += 256) {
        int tok = id >> 4, c2 = (id & 15) << 1;
        int i_img = (tc8 << 2) + (tok >> 5);
        float g0 = G[tok][i_img - c2 + 31];
        float g1 = G[tok][i_img - c2 + 30];
        unsigned pk = (unsigned)f2bf(g0) | ((unsigned)f2bf(g1) << 16);
        *(unsigned*)&qhb[(((size_t)bh << 10) + tok0 + tok) * 32 + c2] = pk;
    }
    __syncthreads();

    // ---- G_w ----
#pragma unroll
    for (int mt = 0; mt < 2; ++mt)
#pragma unroll
        for (int nt = 0; nt < 4; ++nt)
#pragma unroll
            for (int i = 0; i < 4; ++i)
                G[r0 + mt * 16 + quad * 4 + i][nt * 16 + col16] = aw[mt][nt][i];
    __syncthreads();
    for (int id = t; id < 2048; id += 256) {
        int tok = id >> 4, c2 = (id & 15) << 1;
        int j = tok & 31;
        float g0 = G[tok][j - c2 + 31];
        float g1 = G[tok][j - c2 + 30];
        unsigned pk = (unsigned)f2bf(g0) | ((unsigned)f2bf(g1) << 16);
        *(unsigned*)&qwb[(((size_t)bh << 10) + tok0 + tok) * 32 + c2] = pk;
    }
}

// ---------------------------------------------------------------------------
// R19 attention (unchanged — verified): swapped QK^T, P in regs, XOR-swizzled
// Ks/Vs (stride 64), 6 blocks/CU.
// ---------------------------------------------------------------------------
__global__ __launch_bounds__(256, 6) void attn_mfma(
    const unsigned short* __restrict__ Q, const unsigned short* __restrict__ K,
    const unsigned short* __restrict__ Vt,
    const unsigned short* __restrict__ qhb, const unsigned short* __restrict__ qwb,
    unsigned short* __restrict__ Out)
{
    const int t  = threadIdx.x;
    const int id  = blockIdx.x;           // 0..1535
    const int xcd = id & 7;
    const int wq  = id >> 3;
    const int bh  = xcd * 12 + (wq % 12);
    const int qt2 = wq / 12;
    const int b   = bh / 12;
    const int h   = bh - b * 12;
    const int q0  = qt2 << 6;

    __shared__ __align__(16) unsigned short Ks[64 * 64];
    __shared__ __align__(16) unsigned short Vs[64 * 64];
    __shared__ float qh_s[64][33];

    const unsigned short* Kp = K  + (size_t)bh * 65536;
    const unsigned short* Vp = Vt + (size_t)bh * 65536;

    {
        const unsigned* qhp = (const unsigned*)(qhb + ((size_t)bh * 1024 + q0) * 32);
        for (int i2 = t; i2 < 1024; i2 += 256) {
            int row = i2 >> 4, c2 = (i2 & 15) << 1;
            unsigned ph = qhp[i2];
            qh_s[row][c2]     = bf2f((unsigned short)(ph & 0xffff)) - EOFF;
            qh_s[row][c2 + 1] = bf2f((unsigned short)(ph >> 16))    - EOFF;
        }
    }

    const int wv = t >> 6;
    const int lane = t & 63;
    const int c  = lane & 15;
    const int qd = lane >> 4;

    s8v qf0, qf1;
    float uw[8];
    {
        const size_t row = (size_t)bh * 1024 + q0 + (wv << 4) + c;
        const unsigned short* qp = Q + row * 64 + qd * 8;
        qf0 = *(const s8v*)qp;
        qf1 = *(const s8v*)(qp + 32);
        s8v w8 = *(const s8v*)(qwb + row * 32 + qd * 8);
#pragma unroll
        for (int j = 0; j < 8; ++j) uw[j] = bf2f((unsigned short)w8[j]);
    }

    // swizzled LDS addressing: addr(row, col8) = row*64 + ((col8^(row&7))<<3)
    const int xlo = (qd     ^ (c & 7)) << 3;   // read col offset, d 0..31
    const int xhi = ((qd+4) ^ (c & 7)) << 3;   // read col offset, d 32..63

    const int e0 = t * 8, e1 = t * 8 + 2048;
    const int g0 = e0 >> 6, g1 = e1 >> 6;
    const int c8 = t & 7;                      // col8 for writes (s = 8*c8)
    const int s0 = c8 << 3, s1 = s0;           // global col offsets
    const int L0 = (g0 & 32) | ((g0 & 4) << 2) | ((g0 & 24) >> 1) | (g0 & 3);
    const int L1 = (g1 & 32) | ((g1 & 4) << 2) | ((g1 & 24) >> 1) | (g1 & 3);
    const int kw0 = L0 * 64 + ((c8 ^ (L0 & 7)) << 3);
    const int kw1 = L1 * 64 + ((c8 ^ (L1 & 7)) << 3);
    const int vw0 = g0 * 64 + ((c8 ^ (g0 & 7)) << 3);
    const int vw1 = g1 * 64 + ((c8 ^ (g1 & 7)) << 3);
    {
        uint4 pk0 = *(const uint4*)(Kp + e0);
        uint4 pk1 = *(const uint4*)(Kp + e1);
        uint4 pv0 = *(const uint4*)(Vp + (size_t)g0 * 1024 + s0);
        uint4 pv1 = *(const uint4*)(Vp + (size_t)g1 * 1024 + s1);
        *(uint4*)&Ks[kw0] = pk0;
        *(uint4*)&Ks[kw1] = pk1;
        *(uint4*)&Vs[vw0] = pv0;
        *(uint4*)&Vs[vw1] = pv1;
    }
    __syncthreads();

    f4v o[4];
#pragma unroll
    for (int dt = 0; dt < 4; ++dt) { o[dt][0] = 0.f; o[dt][1] = 0.f; o[dt][2] = 0.f; o[dt][3] = 0.f; }
    float lp = 0.f;

    for (int kt = 0; kt < 16; ++kt) {
        uint4 pk0, pk1, pv0, pv1;
        if (kt < 15) {
            const int k0n = (kt + 1) << 6;
            pk0 = *(const uint4*)(Kp + (size_t)k0n * 64 + e0);
            pk1 = *(const uint4*)(Kp + (size_t)k0n * 64 + e1);
            pv0 = *(const uint4*)(Vp + (size_t)g0 * 1024 + k0n + s0);
            pv1 = *(const uint4*)(Vp + (size_t)g1 * 1024 + k0n + s1);
        }

        f4v sc[4];
#pragma unroll
        for (int T = 0; T < 4; ++T) {
            s8v lo = *(const s8v*)&Ks[(T * 16 + c) * 64 + xlo];
            s8v hi = *(const s8v*)&Ks[(T * 16 + c) * 64 + xhi];
            f4v z; z[0] = 0.f; z[1] = 0.f; z[2] = 0.f; z[3] = 0.f;
            z = __builtin_amdgcn_mfma_f32_16x16x32_bf16(lo, qf0, z, 0, 0, 0);
            z = __builtin_amdgcn_mfma_f32_16x16x32_bf16(hi, qf1, z, 0, 0, 0);
            sc[T] = z;
        }

        const float qhv0 = qh_s[(wv << 4) + c][(kt << 1)];
        const float qhv1 = qh_s[(wv << 4) + c][(kt << 1) + 1];

        s8v pa0, pa1;
#pragma unroll
        for (int j = 0; j < 4; ++j) {
            float pe = __builtin_amdgcn_exp2f(sc[0][j] + qhv0 + uw[j]);
            lp += pe; pa0[j] = (short)f2bf(pe);
        }
#pragma unroll
        for (int j = 0; j < 4; ++j) {
            float pe = __builtin_amdgcn_exp2f(sc[1][j] + qhv0 + uw[4 + j]);
            lp += pe; pa0[4 + j] = (short)f2bf(pe);
        }
#pragma unroll
        for (int j = 0; j < 4; ++j) {
            float pe = __builtin_amdgcn_exp2f(sc[2][j] + qhv1 + uw[j]);
            lp += pe; pa1[j] = (short)f2bf(pe);
        }
#pragma unroll
        for (int j = 0; j < 4; ++j) {
            float pe = __builtin_amdgcn_exp2f(sc[3][j] + qhv1 + uw[4 + j]);
            lp += pe; pa1[4 + j] = (short)f2bf(pe);
        }

#pragma unroll
        for (int dt = 0; dt < 4; ++dt) {
            s8v vlo = *(const s8v*)&Vs[(dt * 16 + c) * 64 + xlo];
            s8v vhi = *(const s8v*)&Vs[(dt * 16 + c) * 64 + xhi];
            o[dt] = __builtin_amdgcn_mfma_f32_16x16x32_bf16(pa0, vlo, o[dt], 0, 0, 0);
            o[dt] = __builtin_amdgcn_mfma_f32_16x16x32_bf16(pa1, vhi, o[dt], 0, 0, 0);
        }

        __syncthreads();
        if (kt < 15) {
            *(uint4*)&Ks[kw0] = pk0;
            *(uint4*)&Ks[kw1] = pk1;
            *(uint4*)&Vs[vw0] = pv0;
            *(uint4*)&Vs[vw1] = pv1;
        }
        __syncthreads();
    }

    lp += __shfl_xor(lp, 16);
    lp += __shfl_xor(lp, 32);

#pragma unroll
    for (int i = 0; i < 4; ++i) {
        float inv = 1.f / __shfl(lp, (qd << 2) + i);
        int qr = q0 + (wv << 4) + (qd << 2) + i;
        unsigned short* dst = Out + ((size_t)b * 1024 + qr) * 768 + h * 64;
#pragma unroll
        for (int dt = 0; dt < 4; ++dt)
            dst[dt * 16 + c] = f2bf(o[dt][i] * inv);
    }
}

extern "C" void kernel_launch(void* const* d_in, const int* in_sizes, int n_in,
                              void* d_out, int out_size, void* d_ws, size_t ws_size,
                              hipStream_t stream) {
    const float* x      = (const float*)d_in[0];
    const float* qkv_w  = (const float*)d_in[1];
    const float* qkv_b  = (const float*)d_in[2];
    const float* proj_w = (const float*)d_in[3];
    const float* proj_b = (const float*)d_in[4];
    const float* rel_h  = (const float*)d_in[5];
    const float* rel_w  = (const float*)d_in[6];
    float* out = (float*)d_out;

    char* ws = (char*)d_ws;
    unsigned short* qbuf  = (unsigned short*)(ws);             // bf16 [96][1024][64] 12582912
    unsigned short* kbuf  = (unsigned short*)(ws + 12582912);  // bf16 [96][1024][64] 12582912
    unsigned short* vtbuf = (unsigned short*)(ws + 25165824);  // bf16 [96][64][1024] 12582912
    unsigned short* xab   = (unsigned short*)(ws + 37748736);  // bf16 x / attn-out   12582912
    unsigned short* wqb   = (unsigned short*)(ws + 50331648);  // bf16 qkv_w          3538944
    unsigned short* wpb   = (unsigned short*)(ws + 53870592);  // bf16 proj_w         1179648
    unsigned short* qhb   = (unsigned short*)(ws + 55050240);  // bf16 [96][1024][32] 6291456
    unsigned short* qwb   = (unsigned short*)(ws + 61341696);  // bf16 [96][1024][32] 6291456

    to_bf16_all<<<4224, 256, 0, stream>>>(x, qkv_w, proj_w, xab, wqb, wpb);
    qkv_gemm_mfma<<<288, 512, 0, stream>>>(xab, wqb, qkv_b, qbuf, kbuf, vtbuf);
    bias_prep_mfma<<<dim3(8, 96), 256, 0, stream>>>(qbuf, rel_h, rel_w, qhb, qwb);
    attn_mfma<<<1536, 256, 0, stream>>>(qbuf, kbuf, vtbuf, qhb, qwb, xab);
    proj_gemm_mfma<<<192, 512, 0, stream>>>(xab, wpb, proj_b, out);
}

// Round 14
// 206.599 us; speedup vs baseline: 1.0783x; 1.0783x over previous
//
#include <hip/hip_runtime.h>
#include <cstddef>

typedef short s4v __attribute__((ext_vector_type(4)));
typedef short s8v __attribute__((ext_vector_type(8)));
typedef float f4v __attribute__((ext_vector_type(4)));

__device__ __forceinline__ unsigned short f2bf(float f) {
    union { float f; unsigned u; } v; v.f = f;
    unsigned r = v.u + 0x7fff + ((v.u >> 16) & 1);
    return (unsigned short)(r >> 16);
}
__device__ __forceinline__ float bf2f(unsigned short u) {
    union { unsigned u; float f; } v; v.u = ((unsigned)u) << 16;
    return v.f;
}

// async global->LDS, 16B per lane. LDS dest is wave-uniform base + lane*16.
__device__ __forceinline__ void gl_lds16(const void* g, void* l) {
    __builtin_amdgcn_global_load_lds(
        (const __attribute__((address_space(1))) void*)g,
        (__attribute__((address_space(3))) void*)l, 16, 0, 0);
}

#define QSC   0.18033688011112043f   /* 0.125 * log2(e) */
#define EOFF  23.082320654223414f    /* 16 * log2(e) */

// ---------------------------------------------------------------------------
// Fused f32 -> bf16 conversion for x, qkv_w, proj_w (one launch).
// ---------------------------------------------------------------------------
__global__ __launch_bounds__(256) void to_bf16_all(
    const float* __restrict__ x, const float* __restrict__ qw,
    const float* __restrict__ pw, unsigned short* __restrict__ xd,
    unsigned short* __restrict__ qd, unsigned short* __restrict__ pd)
{
    int i = blockIdx.x * 256 + threadIdx.x;
    const float* s; unsigned short* d; int j;
    if (i < 786432)       { s = x;  d = xd; j = i; }
    else if (i < 1007616) { s = qw; d = qd; j = i - 786432; }
    else                  { s = pw; d = pd; j = i - 1007616; }
    float4 f0 = ((const float4*)s)[j * 2];
    float4 f1 = ((const float4*)s)[j * 2 + 1];
    uint4 pk;
    pk.x = (unsigned)f2bf(f0.x) | ((unsigned)f2bf(f0.y) << 16);
    pk.y = (unsigned)f2bf(f0.z) | ((unsigned)f2bf(f0.w) << 16);
    pk.z = (unsigned)f2bf(f1.x) | ((unsigned)f2bf(f1.y) << 16);
    pk.w = (unsigned)f2bf(f1.z) | ((unsigned)f2bf(f1.w) << 16);
    ((uint4*)d)[j] = pk;
}

// ---------------------------------------------------------------------------
// R21 qkv GEMM = R18 (measured 53.3µs best config): 256x128, 8 waves,
// triple-buffered LDS, counted vmcnt(6), raw barriers (prefetch depth 2).
// ---------------------------------------------------------------------------
__global__ __launch_bounds__(512) void qkv_gemm_mfma(
    const unsigned short* __restrict__ A, const unsigned short* __restrict__ W,
    const float* __restrict__ bias,
    unsigned short* __restrict__ qb, unsigned short* __restrict__ kb,
    unsigned short* __restrict__ vt)
{
    __shared__ __align__(16) unsigned short As[3][256 * 32];
    __shared__ __align__(16) unsigned short Bs[3][128 * 32];
    const int t     = threadIdx.x;
    const int lin   = blockIdx.x;   // 0..575
    const int xcd   = lin & 7;
    const int sq    = lin >> 3;     // 0..71
    const int br    = (xcd << 2) + (sq & 3);   // row-tile 0..31 (256 rows)
    const int bc    = sq >> 2;                 // col-tile 0..17 (128 cols)
    const int wv    = t >> 6;       // 0..7
    const int lane  = t & 63;
    const int col16 = lane & 15;
    const int quad  = lane >> 4;
    const int w4    = lane >> 2;
    const int k8    = (lane & 3) << 3;
    const int mw    = wv >> 1;      // 0..3
    const int nw    = wv & 1;       // 0..1

    const unsigned short* Ag = A + (size_t)(br * 256 + (wv << 5) + w4) * 768 + k8;
    const unsigned short* Wg = W + (size_t)(bc * 128 + (wv << 4) + w4) * 768 + k8;
    const int woA = (wv << 5) * 32;
    const int woB = (wv << 4) * 32;

    f4v acc[4][4];
#pragma unroll
    for (int mt = 0; mt < 4; ++mt)
#pragma unroll
        for (int nt = 0; nt < 4; ++nt) {
            acc[mt][nt][0] = 0.f; acc[mt][nt][1] = 0.f;
            acc[mt][nt][2] = 0.f; acc[mt][nt][3] = 0.f;
        }

    // prologue: stage k-steps 0 and 1 (6 loads/wave in flight)
    gl_lds16(Ag,                 &As[0][woA]);
    gl_lds16(Ag + 16 * 768,      &As[0][woA + 16 * 32]);
    gl_lds16(Wg,                 &Bs[0][woB]);
    gl_lds16(Ag + 32,            &As[1][woA]);
    gl_lds16(Ag + 32 + 16 * 768, &As[1][woA + 16 * 32]);
    gl_lds16(Wg + 32,            &Bs[1][woB]);

#pragma unroll
    for (int kt = 0; kt < 24; ++kt) {
        if (kt < 22) {
            const int nb = (kt + 2) % 3;
            const int ko = (kt + 2) * 32;
            gl_lds16(Ag + ko,            &As[nb][woA]);
            gl_lds16(Ag + ko + 16 * 768, &As[nb][woA + 16 * 32]);
            gl_lds16(Wg + ko,            &Bs[nb][woB]);
        }
        if (kt < 22)       asm volatile("s_waitcnt vmcnt(6)" ::: "memory");
        else if (kt == 22) asm volatile("s_waitcnt vmcnt(3)" ::: "memory");
        else               asm volatile("s_waitcnt vmcnt(0)" ::: "memory");
        __builtin_amdgcn_s_barrier();
        asm volatile("" ::: "memory");

        const unsigned short* Ab = As[kt % 3];
        const unsigned short* Bb = Bs[kt % 3];
        s8v a[4], b[4];
#pragma unroll
        for (int mt = 0; mt < 4; ++mt)
            a[mt] = *(const s8v*)&Ab[(mw * 64 + mt * 16 + col16) * 32 + quad * 8];
#pragma unroll
        for (int nt = 0; nt < 4; ++nt)
            b[nt] = *(const s8v*)&Bb[(nw * 64 + nt * 16 + col16) * 32 + quad * 8];
#pragma unroll
        for (int mt = 0; mt < 4; ++mt)
#pragma unroll
            for (int nt = 0; nt < 4; ++nt)
                acc[mt][nt] = __builtin_amdgcn_mfma_f32_16x16x32_bf16(
                    a[mt], b[nt], acc[mt][nt], 0, 0, 0);

        asm volatile("" ::: "memory");
        __builtin_amdgcn_s_barrier();
    }

    const int which = bc / 6;
    const int cb    = (bc % 6) * 128 + nw * 64;
    const int m0    = br * 256 + mw * 64 + quad * 4;
    if (which == 2) {
        // V transposed: [bh][d][tok], 4 consecutive toks per b64 store
#pragma unroll
        for (int nt = 0; nt < 4; ++nt) {
            int c    = cb + nt * 16 + col16;
            int head = c >> 6, d = c & 63;
            float bv = bias[1536 + c];
#pragma unroll
            for (int mt = 0; mt < 4; ++mt) {
                int mb  = m0 + mt * 16;
                int bbk = mb >> 10, tok = mb & 1023;
                uint2 pk;
                pk.x = (unsigned)f2bf(acc[mt][nt][0] + bv)
                     | ((unsigned)f2bf(acc[mt][nt][1] + bv) << 16);
                pk.y = (unsigned)f2bf(acc[mt][nt][2] + bv)
                     | ((unsigned)f2bf(acc[mt][nt][3] + bv) << 16);
                *(uint2*)&vt[((size_t)(bbk * 12 + head)) * 65536 + (size_t)d * 1024 + tok] = pk;
            }
        }
    } else {
        // q carries 0.125*log2e so downstream softmax can use exp2 directly
        const float sc = (which == 0) ? QSC : 1.0f;
        unsigned short* dst = (which == 0) ? qb : kb;
#pragma unroll
        for (int nt = 0; nt < 4; ++nt) {
            int c    = cb + nt * 16 + col16;
            int head = c >> 6, d = c & 63;
            float bv = bias[which * 768 + c];
#pragma unroll
            for (int mt = 0; mt < 4; ++mt) {
#pragma unroll
                for (int i = 0; i < 4; ++i) {
                    int m   = m0 + mt * 16 + i;
                    int bbk = m >> 10, tok = m & 1023;
                    dst[(((size_t)(bbk * 12 + head) << 10) + tok) * 64 + d] =
                        f2bf((acc[mt][nt][i] + bv) * sc);
                }
            }
        }
    }
}

// ---------------------------------------------------------------------------
// R18 proj GEMM (unchanged): 256x128, triple-buffer depth-2 counted vmcnt.
// ---------------------------------------------------------------------------
__global__ __launch_bounds__(512) void proj_gemm_mfma(
    const unsigned short* __restrict__ A, const unsigned short* __restrict__ W,
    const float* __restrict__ bias, float* __restrict__ Out)
{
    __shared__ __align__(16) unsigned short As[3][256 * 32];
    __shared__ __align__(16) unsigned short Bs[3][128 * 32];
    const int t     = threadIdx.x;
    const int lin   = blockIdx.x;   // 0..191
    const int xcd   = lin & 7;
    const int sq    = lin >> 3;     // 0..23
    const int br    = (xcd << 2) + (sq & 3);   // 0..31
    const int bc    = sq >> 2;                 // 0..5
    const int wv    = t >> 6;
    const int lane  = t & 63;
    const int col16 = lane & 15;
    const int quad  = lane >> 4;
    const int w4    = lane >> 2;
    const int k8    = (lane & 3) << 3;
    const int mw    = wv >> 1, nw = wv & 1;

    const unsigned short* Ag = A + (size_t)(br * 256 + (wv << 5) + w4) * 768 + k8;
    const unsigned short* Wg = W + (size_t)(bc * 128 + (wv << 4) + w4) * 768 + k8;
    const int woA = (wv << 5) * 32;
    const int woB = (wv << 4) * 32;

    f4v acc[4][4];
#pragma unroll
    for (int mt = 0; mt < 4; ++mt)
#pragma unroll
        for (int nt = 0; nt < 4; ++nt) {
            acc[mt][nt][0] = 0.f; acc[mt][nt][1] = 0.f;
            acc[mt][nt][2] = 0.f; acc[mt][nt][3] = 0.f;
        }

    gl_lds16(Ag,                 &As[0][woA]);
    gl_lds16(Ag + 16 * 768,      &As[0][woA + 16 * 32]);
    gl_lds16(Wg,                 &Bs[0][woB]);
    gl_lds16(Ag + 32,            &As[1][woA]);
    gl_lds16(Ag + 32 + 16 * 768, &As[1][woA + 16 * 32]);
    gl_lds16(Wg + 32,            &Bs[1][woB]);

#pragma unroll
    for (int kt = 0; kt < 24; ++kt) {
        if (kt < 22) {
            const int nb = (kt + 2) % 3;
            const int ko = (kt + 2) * 32;
            gl_lds16(Ag + ko,            &As[nb][woA]);
            gl_lds16(Ag + ko + 16 * 768, &As[nb][woA + 16 * 32]);
            gl_lds16(Wg + ko,            &Bs[nb][woB]);
        }
        if (kt < 22)       asm volatile("s_waitcnt vmcnt(6)" ::: "memory");
        else if (kt == 22) asm volatile("s_waitcnt vmcnt(3)" ::: "memory");
        else               asm volatile("s_waitcnt vmcnt(0)" ::: "memory");
        __builtin_amdgcn_s_barrier();
        asm volatile("" ::: "memory");

        const unsigned short* Ab = As[kt % 3];
        const unsigned short* Bb = Bs[kt % 3];
        s8v a[4], b[4];
#pragma unroll
        for (int mt = 0; mt < 4; ++mt)
            a[mt] = *(const s8v*)&Ab[(mw * 64 + mt * 16 + col16) * 32 + quad * 8];
#pragma unroll
        for (int nt = 0; nt < 4; ++nt)
            b[nt] = *(const s8v*)&Bb[(nw * 64 + nt * 16 + col16) * 32 + quad * 8];
#pragma unroll
        for (int mt = 0; mt < 4; ++mt)
#pragma unroll
            for (int nt = 0; nt < 4; ++nt)
                acc[mt][nt] = __builtin_amdgcn_mfma_f32_16x16x32_bf16(
                    a[mt], b[nt], acc[mt][nt], 0, 0, 0);

        asm volatile("" ::: "memory");
        __builtin_amdgcn_s_barrier();
    }

    const int m0 = br * 256 + mw * 64 + quad * 4;
#pragma unroll
    for (int nt = 0; nt < 4; ++nt) {
        int c    = bc * 128 + nw * 64 + nt * 16 + col16;
        float bv = bias[c];
#pragma unroll
        for (int mt = 0; mt < 4; ++mt) {
#pragma unroll
            for (int i = 0; i < 4; ++i) {
                int m = m0 + mt * 16 + i;
                Out[(size_t)m * 768 + c] = acc[mt][nt][i] + bv;
            }
        }
    }
}

// ---------------------------------------------------------------------------
// Bias-table precompute via MFMA (unchanged).
// ---------------------------------------------------------------------------
__global__ __launch_bounds__(256) void bias_prep_mfma(
    const unsigned short* __restrict__ Q, const float* __restrict__ Rh,
    const float* __restrict__ Rw, unsigned short* __restrict__ qhb,
    unsigned short* __restrict__ qwb)
{
    __shared__ __align__(16) char smem[36864];
    unsigned short (*Qs)[72]  = (unsigned short (*)[72])smem;
    unsigned short (*Rs)[72]  = (unsigned short (*)[72])(smem + 18432);
    unsigned short (*Wsm)[72] = (unsigned short (*)[72])(smem + 27648);
    float (*G)[66]            = (float (*)[66])smem;

    const int t    = threadIdx.x;
    const int tc8  = blockIdx.x;   // 0..7 : 128-token chunk
    const int bh   = blockIdx.y;   // 0..95
    const int tok0 = tc8 << 7;

    for (int id = t; id < 1024; id += 256) {
        int row = id >> 3, g8 = (id & 7) << 3;
        *(uint4*)&Qs[row][g8] =
            *(const uint4*)(Q + ((size_t)bh * 1024 + tok0 + row) * 64 + g8);
    }
    for (int id = t; id < 512; id += 256) {
        int row = id >> 3, g8 = (id & 7) << 3;
        unsigned short* dh = &Rs[row][g8];
        unsigned short* dw = &Wsm[row][g8];
        if (row < 63) {
            const float* sh = Rh + row * 64 + g8;
            const float* sw = Rw + row * 64 + g8;
            float4 a = *(const float4*)sh; float4 b = *(const float4*)(sh + 4);
            float4 c = *(const float4*)sw; float4 d = *(const float4*)(sw + 4);
            dh[0] = f2bf(a.x); dh[1] = f2bf(a.y); dh[2] = f2bf(a.z); dh[3] = f2bf(a.w);
            dh[4] = f2bf(b.x); dh[5] = f2bf(b.y); dh[6] = f2bf(b.z); dh[7] = f2bf(b.w);
            dw[0] = f2bf(c.x); dw[1] = f2bf(c.y); dw[2] = f2bf(c.z); dw[3] = f2bf(c.w);
            dw[4] = f2bf(d.x); dw[5] = f2bf(d.y); dw[6] = f2bf(d.z); dw[7] = f2bf(d.w);
        } else {
#pragma unroll
            for (int j = 0; j < 8; ++j) { dh[j] = 0; dw[j] = 0; }
        }
    }
    __syncthreads();

    const int wv    = t >> 6;
    const int lane  = t & 63;
    const int col16 = lane & 15;
    const int quad  = lane >> 4;
    const int r0    = wv << 5;

    s8v qa[2][2], rb[4][2], wb[4][2];
#pragma unroll
    for (int mt = 0; mt < 2; ++mt)
#pragma unroll
        for (int kc = 0; kc < 2; ++kc)
            qa[mt][kc] = *(const s8v*)&Qs[r0 + mt * 16 + col16][kc * 32 + quad * 8];
#pragma unroll
    for (int nt = 0; nt < 4; ++nt)
#pragma unroll
        for (int kc = 0; kc < 2; ++kc) {
            rb[nt][kc] = *(const s8v*)&Rs[nt * 16 + col16][kc * 32 + quad * 8];
            wb[nt][kc] = *(const s8v*)&Wsm[nt * 16 + col16][kc * 32 + quad * 8];
        }

    f4v ah[2][4], aw[2][4];
#pragma unroll
    for (int mt = 0; mt < 2; ++mt)
#pragma unroll
        for (int nt = 0; nt < 4; ++nt) {
            f4v z; z[0] = 0.f; z[1] = 0.f; z[2] = 0.f; z[3] = 0.f;
            ah[mt][nt] = z; aw[mt][nt] = z;
        }
#pragma unroll
    for (int mt = 0; mt < 2; ++mt)
#pragma unroll
        for (int nt = 0; nt < 4; ++nt) {
            ah[mt][nt] = __builtin_amdgcn_mfma_f32_16x16x32_bf16(qa[mt][0], rb[nt][0], ah[mt][nt], 0, 0, 0);
            ah[mt][nt] = __builtin_amdgcn_mfma_f32_16x16x32_bf16(qa[mt][1], rb[nt][1], ah[mt][nt], 0, 0, 0);
            aw[mt][nt] = __builtin_amdgcn_mfma_f32_16x16x32_bf16(qa[mt][0], wb[nt][0], aw[mt][nt], 0, 0, 0);
            aw[mt][nt] = __builtin_amdgcn_mfma_f32_16x16x32_bf16(qa[mt][1], wb[nt][1], aw[mt][nt], 0, 0, 0);
        }
    __syncthreads();

    // ---- G_h ----
#pragma unroll
    for (int mt = 0; mt < 2; ++mt)
#pragma unroll
        for (int nt = 0; nt < 4; ++nt)
#pragma unroll
            for (int i = 0; i < 4; ++i)
                G[r0 + mt * 16 + quad * 4 + i][nt * 16 + col16] = ah[mt][nt][i];
    __syncthreads();
    for (int id = t; id < 2048; id += 256) {
        int tok = id >> 4, c2 = (id & 15) << 1;
        int i_img = (tc8 << 2) + (tok >> 5);
        float g0 = G[tok][i_img - c2 + 31];
        float g1 = G[tok][i_img - c2 + 30];
        unsigned pk = (unsigned)f2bf(g0) | ((unsigned)f2bf(g1) << 16);
        *(unsigned*)&qhb[(((size_t)bh << 10) + tok0 + tok) * 32 + c2] = pk;
    }
    __syncthreads();

    // ---- G_w ----
#pragma unroll
    for (int mt = 0; mt < 2; ++mt)
#pragma unroll
        for (int nt = 0; nt < 4; ++nt)
#pragma unroll
            for (int i = 0; i < 4; ++i)
                G[r0 + mt * 16 + quad * 4 + i][nt * 16 + col16] = aw[mt][nt][i];
    __syncthreads();
    for (int id = t; id < 2048; id += 256) {
        int tok = id >> 4, c2 = (id & 15) << 1;
        int j = tok & 31;
        float g0 = G[tok][j - c2 + 31];
        float g1 = G[tok][j - c2 + 30];
        unsigned pk = (unsigned)f2bf(g0) | ((unsigned)f2bf(g1) << 16);
        *(unsigned*)&qwb[(((size_t)bh << 10) + tok0 + tok) * 32 + c2] = pk;
    }
}

// ---------------------------------------------------------------------------
// R21 attention (resubmit — R13 was an infra failure, kernel never ran):
// q-tile 128/block (each wave owns 32 q rows = 2 q-groups), SAME K/V LDS
// reads per wave -> LDS traffic per q-row HALVES (R10 counters showed attn
// LDS-pipe bound: all waves read identical K/V frags). Grid 768 = 3
// blocks/CU exact (12 waves/CU). Swizzled Ks/Vs + swapped QK^T + P-in-regs
// unchanged (verified R19 structure; second q-group is +16 rows).
// ---------------------------------------------------------------------------
__global__ __launch_bounds__(256, 3) void attn_mfma(
    const unsigned short* __restrict__ Q, const unsigned short* __restrict__ K,
    const unsigned short* __restrict__ Vt,
    const unsigned short* __restrict__ qhb, const unsigned short* __restrict__ qwb,
    unsigned short* __restrict__ Out)
{
    const int t  = threadIdx.x;
    const int id  = blockIdx.x;           // 0..767
    const int xcd = id & 7;
    const int wq  = id >> 3;              // 0..95
    const int bh  = xcd * 12 + (wq % 12);
    const int qt  = wq / 12;              // 0..7
    const int b   = bh / 12;
    const int h   = bh - b * 12;
    const int q0  = qt << 7;              // 128-row q tile

    __shared__ __align__(16) unsigned short Ks[64 * 64];
    __shared__ __align__(16) unsigned short Vs[64 * 64];
    __shared__ float qh_s[128][33];

    const unsigned short* Kp = K  + (size_t)bh * 65536;
    const unsigned short* Vp = Vt + (size_t)bh * 65536;

    {
        const unsigned* qhp = (const unsigned*)(qhb + ((size_t)bh * 1024 + q0) * 32);
        for (int i2 = t; i2 < 2048; i2 += 256) {
            int row = i2 >> 4, c2 = (i2 & 15) << 1;
            unsigned ph = qhp[i2];
            qh_s[row][c2]     = bf2f((unsigned short)(ph & 0xffff)) - EOFF;
            qh_s[row][c2 + 1] = bf2f((unsigned short)(ph >> 16))    - EOFF;
        }
    }

    const int wv = t >> 6;
    const int lane = t & 63;
    const int c  = lane & 15;
    const int qd = lane >> 4;

    // two q-groups per wave: rows q0 + wv*32 + qg*16 + c
    s8v qfA0, qfA1, qfB0, qfB1;
    float uwA[8], uwB[8];
    {
        const size_t rowA = (size_t)bh * 1024 + q0 + (wv << 5) + c;
        const unsigned short* qpA = Q + rowA * 64 + qd * 8;
        qfA0 = *(const s8v*)qpA;
        qfA1 = *(const s8v*)(qpA + 32);
        s8v w8A = *(const s8v*)(qwb + rowA * 32 + qd * 8);
        const size_t rowB = rowA + 16;
        const unsigned short* qpB = Q + rowB * 64 + qd * 8;
        qfB0 = *(const s8v*)qpB;
        qfB1 = *(const s8v*)(qpB + 32);
        s8v w8B = *(const s8v*)(qwb + rowB * 32 + qd * 8);
#pragma unroll
        for (int j = 0; j < 8; ++j) { uwA[j] = bf2f((unsigned short)w8A[j]);
                                      uwB[j] = bf2f((unsigned short)w8B[j]); }
    }

    // swizzled LDS addressing: addr(row, col8) = row*64 + ((col8^(row&7))<<3)
    const int xlo = (qd     ^ (c & 7)) << 3;
    const int xhi = ((qd+4) ^ (c & 7)) << 3;

    const int e0 = t * 8, e1 = t * 8 + 2048;
    const int g0 = e0 >> 6, g1 = e1 >> 6;
    const int c8 = t & 7;
    const int s0 = c8 << 3;
    const int L0 = (g0 & 32) | ((g0 & 4) << 2) | ((g0 & 24) >> 1) | (g0 & 3);
    const int L1 = (g1 & 32) | ((g1 & 4) << 2) | ((g1 & 24) >> 1) | (g1 & 3);
    const int kw0 = L0 * 64 + ((c8 ^ (L0 & 7)) << 3);
    const int kw1 = L1 * 64 + ((c8 ^ (L1 & 7)) << 3);
    const int vw0 = g0 * 64 + ((c8 ^ (g0 & 7)) << 3);
    const int vw1 = g1 * 64 + ((c8 ^ (g1 & 7)) << 3);
    {
        uint4 pk0 = *(const uint4*)(Kp + e0);
        uint4 pk1 = *(const uint4*)(Kp + e1);
        uint4 pv0 = *(const uint4*)(Vp + (size_t)g0 * 1024 + s0);
        uint4 pv1 = *(const uint4*)(Vp + (size_t)g1 * 1024 + s0);
        *(uint4*)&Ks[kw0] = pk0;
        *(uint4*)&Ks[kw1] = pk1;
        *(uint4*)&Vs[vw0] = pv0;
        *(uint4*)&Vs[vw1] = pv1;
    }
    __syncthreads();

    f4v o[2][4];
#pragma unroll
    for (int qg = 0; qg < 2; ++qg)
#pragma unroll
        for (int dt = 0; dt < 4; ++dt) {
            o[qg][dt][0] = 0.f; o[qg][dt][1] = 0.f;
            o[qg][dt][2] = 0.f; o[qg][dt][3] = 0.f;
        }
    float lp[2] = {0.f, 0.f};

    for (int kt = 0; kt < 16; ++kt) {
        uint4 pk0, pk1, pv0, pv1;
        if (kt < 15) {
            const int k0n = (kt + 1) << 6;
            pk0 = *(const uint4*)(Kp + (size_t)k0n * 64 + e0);
            pk1 = *(const uint4*)(Kp + (size_t)k0n * 64 + e1);
            pv0 = *(const uint4*)(Vp + (size_t)g0 * 1024 + k0n + s0);
            pv1 = *(const uint4*)(Vp + (size_t)g1 * 1024 + k0n + s0);
        }

        // K frags read ONCE, used by both q-groups
        s8v klo[4], khi[4];
#pragma unroll
        for (int T = 0; T < 4; ++T) {
            klo[T] = *(const s8v*)&Ks[(T * 16 + c) * 64 + xlo];
            khi[T] = *(const s8v*)&Ks[(T * 16 + c) * 64 + xhi];
        }

        s8v pa[2][2];
#pragma unroll
        for (int qg = 0; qg < 2; ++qg) {
            const s8v qf0 = qg ? qfB0 : qfA0;
            const s8v qf1 = qg ? qfB1 : qfA1;
            const float* uw = qg ? uwB : uwA;
            const int qrow = (wv << 5) + qg * 16 + c;

            f4v sc[4];
#pragma unroll
            for (int T = 0; T < 4; ++T) {
                f4v z; z[0] = 0.f; z[1] = 0.f; z[2] = 0.f; z[3] = 0.f;
                z = __builtin_amdgcn_mfma_f32_16x16x32_bf16(klo[T], qf0, z, 0, 0, 0);
                z = __builtin_amdgcn_mfma_f32_16x16x32_bf16(khi[T], qf1, z, 0, 0, 0);
                sc[T] = z;
            }

            const float qhv0 = qh_s[qrow][(kt << 1)];
            const float qhv1 = qh_s[qrow][(kt << 1) + 1];

#pragma unroll
            for (int j = 0; j < 4; ++j) {
                float pe = __builtin_amdgcn_exp2f(sc[0][j] + qhv0 + uw[j]);
                lp[qg] += pe; pa[qg][0][j] = (short)f2bf(pe);
            }
#pragma unroll
            for (int j = 0; j < 4; ++j) {
                float pe = __builtin_amdgcn_exp2f(sc[1][j] + qhv0 + uw[4 + j]);
                lp[qg] += pe; pa[qg][0][4 + j] = (short)f2bf(pe);
            }
#pragma unroll
            for (int j = 0; j < 4; ++j) {
                float pe = __builtin_amdgcn_exp2f(sc[2][j] + qhv1 + uw[j]);
                lp[qg] += pe; pa[qg][1][j] = (short)f2bf(pe);
            }
#pragma unroll
            for (int j = 0; j < 4; ++j) {
                float pe = __builtin_amdgcn_exp2f(sc[3][j] + qhv1 + uw[4 + j]);
                lp[qg] += pe; pa[qg][1][4 + j] = (short)f2bf(pe);
            }
        }

        // V frags read ONCE, used by both q-groups
#pragma unroll
        for (int dt = 0; dt < 4; ++dt) {
            s8v vlo = *(const s8v*)&Vs[(dt * 16 + c) * 64 + xlo];
            s8v vhi = *(const s8v*)&Vs[(dt * 16 + c) * 64 + xhi];
#pragma unroll
            for (int qg = 0; qg < 2; ++qg) {
                o[qg][dt] = __builtin_amdgcn_mfma_f32_16x16x32_bf16(pa[qg][0], vlo, o[qg][dt], 0, 0, 0);
                o[qg][dt] = __builtin_amdgcn_mfma_f32_16x16x32_bf16(pa[qg][1], vhi, o[qg][dt], 0, 0, 0);
            }
        }

        __syncthreads();
        if (kt < 15) {
            *(uint4*)&Ks[kw0] = pk0;
            *(uint4*)&Ks[kw1] = pk1;
            *(uint4*)&Vs[vw0] = pv0;
            *(uint4*)&Vs[vw1] = pv1;
        }
        __syncthreads();
    }

#pragma unroll
    for (int qg = 0; qg < 2; ++qg) {
        lp[qg] += __shfl_xor(lp[qg], 16);
        lp[qg] += __shfl_xor(lp[qg], 32);
#pragma unroll
        for (int i = 0; i < 4; ++i) {
            float inv = 1.f / __shfl(lp[qg], (qd << 2) + i);
            int qr = q0 + (wv << 5) + qg * 16 + (qd << 2) + i;
            unsigned short* dst = Out + ((size_t)b * 1024 + qr) * 768 + h * 64;
#pragma unroll
            for (int dt = 0; dt < 4; ++dt)
                dst[dt * 16 + c] = f2bf(o[qg][dt][i] * inv);
        }
    }
}

extern "C" void kernel_launch(void* const* d_in, const int* in_sizes, int n_in,
                              void* d_out, int out_size, void* d_ws, size_t ws_size,
                              hipStream_t stream) {
    const float* x      = (const float*)d_in[0];
    const float* qkv_w  = (const float*)d_in[1];
    const float* qkv_b  = (const float*)d_in[2];
    const float* proj_w = (const float*)d_in[3];
    const float* proj_b = (const float*)d_in[4];
    const float* rel_h  = (const float*)d_in[5];
    const float* rel_w  = (const float*)d_in[6];
    float* out = (float*)d_out;

    char* ws = (char*)d_ws;
    unsigned short* qbuf  = (unsigned short*)(ws);             // bf16 [96][1024][64] 12582912
    unsigned short* kbuf  = (unsigned short*)(ws + 12582912);  // bf16 [96][1024][64] 12582912
    unsigned short* vtbuf = (unsigned short*)(ws + 25165824);  // bf16 [96][64][1024] 12582912
    unsigned short* xab   = (unsigned short*)(ws + 37748736);  // bf16 x / attn-out   12582912
    unsigned short* wqb   = (unsigned short*)(ws + 50331648);  // bf16 qkv_w          3538944
    unsigned short* wpb   = (unsigned short*)(ws + 53870592);  // bf16 proj_w         1179648
    unsigned short* qhb   = (unsigned short*)(ws + 55050240);  // bf16 [96][1024][32] 6291456
    unsigned short* qwb   = (unsigned short*)(ws + 61341696);  // bf16 [96][1024][32] 6291456

    to_bf16_all<<<4224, 256, 0, stream>>>(x, qkv_w, proj_w, xab, wqb, wpb);
    qkv_gemm_mfma<<<576, 512, 0, stream>>>(xab, wqb, qkv_b, qbuf, kbuf, vtbuf);
    bias_prep_mfma<<<dim3(8, 96), 256, 0, stream>>>(qbuf, rel_h, rel_w, qhb, qwb);
    attn_mfma<<<768, 256, 0, stream>>>(qbuf, kbuf, vtbuf, qhb, qwb, xab);
    proj_gemm_mfma<<<192, 512, 0, stream>>>(xab, wpb, proj_b, out);
}

// Round 15
// 204.715 us; speedup vs baseline: 1.0882x; 1.0092x over previous
//
#include <hip/hip_runtime.h>
#include <cstddef>

typedef short s4v __attribute__((ext_vector_type(4)));
typedef short s8v __attribute__((ext_vector_type(8)));
typedef float f4v __attribute__((ext_vector_type(4)));

__device__ __forceinline__ unsigned short f2bf(float f) {
    union { float f; unsigned u; } v; v.f = f;
    unsigned r = v.u + 0x7fff + ((v.u >> 16) & 1);
    return (unsigned short)(r >> 16);
}
__device__ __forceinline__ float bf2f(unsigned short u) {
    union { unsigned u; float f; } v; v.u = ((unsigned)u) << 16;
    return v.f;
}

// async global->LDS, 16B per lane. LDS dest is wave-uniform base + lane*16.
__device__ __forceinline__ void gl_lds16(const void* g, void* l) {
    __builtin_amdgcn_global_load_lds(
        (const __attribute__((address_space(1))) void*)g,
        (__attribute__((address_space(3))) void*)l, 16, 0, 0);
}

#define QSC   0.18033688011112043f   /* 0.125 * log2(e) */
#define EOFF  23.082320654223414f    /* 16 * log2(e) */

// ---------------------------------------------------------------------------
// Fused f32 -> bf16 conversion for x, qkv_w, proj_w (one launch).
// ---------------------------------------------------------------------------
__global__ __launch_bounds__(256) void to_bf16_all(
    const float* __restrict__ x, const float* __restrict__ qw,
    const float* __restrict__ pw, unsigned short* __restrict__ xd,
    unsigned short* __restrict__ qd, unsigned short* __restrict__ pd)
{
    int i = blockIdx.x * 256 + threadIdx.x;
    const float* s; unsigned short* d; int j;
    if (i < 786432)       { s = x;  d = xd; j = i; }
    else if (i < 1007616) { s = qw; d = qd; j = i - 786432; }
    else                  { s = pw; d = pd; j = i - 1007616; }
    float4 f0 = ((const float4*)s)[j * 2];
    float4 f1 = ((const float4*)s)[j * 2 + 1];
    uint4 pk;
    pk.x = (unsigned)f2bf(f0.x) | ((unsigned)f2bf(f0.y) << 16);
    pk.y = (unsigned)f2bf(f0.z) | ((unsigned)f2bf(f0.w) << 16);
    pk.z = (unsigned)f2bf(f1.x) | ((unsigned)f2bf(f1.y) << 16);
    pk.w = (unsigned)f2bf(f1.z) | ((unsigned)f2bf(f1.w) << 16);
    ((uint4*)d)[j] = pk;
}

// ---------------------------------------------------------------------------
// R22 qkv GEMM: 256x128, 8 waves, triple-buffered LDS, depth-2 pipeline —
// now SINGLE barrier per K-step (T3 recipe: stage issued AFTER the barrier,
// before ds_reads; counted vmcnt(3) retires exactly this step's 3-load
// group). Race-free: all waves passing barrier(kt) implies kt-1's ds_reads
// were consumed (compiler lgkmcnt before MFMA), so staging buffer (kt-1)%3
// is safe. Halves barrier count (24 vs 48).
// ---------------------------------------------------------------------------
__global__ __launch_bounds__(512) void qkv_gemm_mfma(
    const unsigned short* __restrict__ A, const unsigned short* __restrict__ W,
    const float* __restrict__ bias,
    unsigned short* __restrict__ qb, unsigned short* __restrict__ kb,
    unsigned short* __restrict__ vt)
{
    __shared__ __align__(16) unsigned short As[3][256 * 32];
    __shared__ __align__(16) unsigned short Bs[3][128 * 32];
    const int t     = threadIdx.x;
    const int lin   = blockIdx.x;   // 0..575
    const int xcd   = lin & 7;
    const int sq    = lin >> 3;     // 0..71
    const int br    = (xcd << 2) + (sq & 3);   // row-tile 0..31 (256 rows)
    const int bc    = sq >> 2;                 // col-tile 0..17 (128 cols)
    const int wv    = t >> 6;       // 0..7
    const int lane  = t & 63;
    const int col16 = lane & 15;
    const int quad  = lane >> 4;
    const int w4    = lane >> 2;
    const int k8    = (lane & 3) << 3;
    const int mw    = wv >> 1;      // 0..3
    const int nw    = wv & 1;       // 0..1

    const unsigned short* Ag = A + (size_t)(br * 256 + (wv << 5) + w4) * 768 + k8;
    const unsigned short* Wg = W + (size_t)(bc * 128 + (wv << 4) + w4) * 768 + k8;
    const int woA = (wv << 5) * 32;
    const int woB = (wv << 4) * 32;

    f4v acc[4][4];
#pragma unroll
    for (int mt = 0; mt < 4; ++mt)
#pragma unroll
        for (int nt = 0; nt < 4; ++nt) {
            acc[mt][nt][0] = 0.f; acc[mt][nt][1] = 0.f;
            acc[mt][nt][2] = 0.f; acc[mt][nt][3] = 0.f;
        }

    // prologue: stage k-steps 0 and 1 (6 loads/wave in flight)
    gl_lds16(Ag,                 &As[0][woA]);
    gl_lds16(Ag + 16 * 768,      &As[0][woA + 16 * 32]);
    gl_lds16(Wg,                 &Bs[0][woB]);
    gl_lds16(Ag + 32,            &As[1][woA]);
    gl_lds16(Ag + 32 + 16 * 768, &As[1][woA + 16 * 32]);
    gl_lds16(Wg + 32,            &Bs[1][woB]);

#pragma unroll
    for (int kt = 0; kt < 24; ++kt) {
        // retire the oldest 3-load group = this step's buffer
        if (kt < 23) asm volatile("s_waitcnt vmcnt(3)" ::: "memory");
        else         asm volatile("s_waitcnt vmcnt(0)" ::: "memory");
        __builtin_amdgcn_s_barrier();
        asm volatile("" ::: "memory");

        // stage kt+2 AFTER the barrier: kt-1's reads of this buffer are done
        if (kt < 22) {
            const int nb = (kt + 2) % 3;
            const int ko = (kt + 2) * 32;
            gl_lds16(Ag + ko,            &As[nb][woA]);
            gl_lds16(Ag + ko + 16 * 768, &As[nb][woA + 16 * 32]);
            gl_lds16(Wg + ko,            &Bs[nb][woB]);
        }

        const unsigned short* Ab = As[kt % 3];
        const unsigned short* Bb = Bs[kt % 3];
        s8v a[4], b[4];
#pragma unroll
        for (int mt = 0; mt < 4; ++mt)
            a[mt] = *(const s8v*)&Ab[(mw * 64 + mt * 16 + col16) * 32 + quad * 8];
#pragma unroll
        for (int nt = 0; nt < 4; ++nt)
            b[nt] = *(const s8v*)&Bb[(nw * 64 + nt * 16 + col16) * 32 + quad * 8];
#pragma unroll
        for (int mt = 0; mt < 4; ++mt)
#pragma unroll
            for (int nt = 0; nt < 4; ++nt)
                acc[mt][nt] = __builtin_amdgcn_mfma_f32_16x16x32_bf16(
                    a[mt], b[nt], acc[mt][nt], 0, 0, 0);
    }

    const int which = bc / 6;
    const int cb    = (bc % 6) * 128 + nw * 64;
    const int m0    = br * 256 + mw * 64 + quad * 4;
    if (which == 2) {
        // V transposed: [bh][d][tok], 4 consecutive toks per b64 store
#pragma unroll
        for (int nt = 0; nt < 4; ++nt) {
            int c    = cb + nt * 16 + col16;
            int head = c >> 6, d = c & 63;
            float bv = bias[1536 + c];
#pragma unroll
            for (int mt = 0; mt < 4; ++mt) {
                int mb  = m0 + mt * 16;
                int bbk = mb >> 10, tok = mb & 1023;
                uint2 pk;
                pk.x = (unsigned)f2bf(acc[mt][nt][0] + bv)
                     | ((unsigned)f2bf(acc[mt][nt][1] + bv) << 16);
                pk.y = (unsigned)f2bf(acc[mt][nt][2] + bv)
                     | ((unsigned)f2bf(acc[mt][nt][3] + bv) << 16);
                *(uint2*)&vt[((size_t)(bbk * 12 + head)) * 65536 + (size_t)d * 1024 + tok] = pk;
            }
        }
    } else {
        // q carries 0.125*log2e so downstream softmax can use exp2 directly
        const float sc = (which == 0) ? QSC : 1.0f;
        unsigned short* dst = (which == 0) ? qb : kb;
#pragma unroll
        for (int nt = 0; nt < 4; ++nt) {
            int c    = cb + nt * 16 + col16;
            int head = c >> 6, d = c & 63;
            float bv = bias[which * 768 + c];
#pragma unroll
            for (int mt = 0; mt < 4; ++mt) {
#pragma unroll
                for (int i = 0; i < 4; ++i) {
                    int m   = m0 + mt * 16 + i;
                    int bbk = m >> 10, tok = m & 1023;
                    dst[(((size_t)(bbk * 12 + head) << 10) + tok) * 64 + d] =
                        f2bf((acc[mt][nt][i] + bv) * sc);
                }
            }
        }
    }
}

// ---------------------------------------------------------------------------
// R22 proj GEMM: same single-barrier counted-vmcnt schedule.
// ---------------------------------------------------------------------------
__global__ __launch_bounds__(512) void proj_gemm_mfma(
    const unsigned short* __restrict__ A, const unsigned short* __restrict__ W,
    const float* __restrict__ bias, float* __restrict__ Out)
{
    __shared__ __align__(16) unsigned short As[3][256 * 32];
    __shared__ __align__(16) unsigned short Bs[3][128 * 32];
    const int t     = threadIdx.x;
    const int lin   = blockIdx.x;   // 0..191
    const int xcd   = lin & 7;
    const int sq    = lin >> 3;     // 0..23
    const int br    = (xcd << 2) + (sq & 3);   // 0..31
    const int bc    = sq >> 2;                 // 0..5
    const int wv    = t >> 6;
    const int lane  = t & 63;
    const int col16 = lane & 15;
    const int quad  = lane >> 4;
    const int w4    = lane >> 2;
    const int k8    = (lane & 3) << 3;
    const int mw    = wv >> 1, nw = wv & 1;

    const unsigned short* Ag = A + (size_t)(br * 256 + (wv << 5) + w4) * 768 + k8;
    const unsigned short* Wg = W + (size_t)(bc * 128 + (wv << 4) + w4) * 768 + k8;
    const int woA = (wv << 5) * 32;
    const int woB = (wv << 4) * 32;

    f4v acc[4][4];
#pragma unroll
    for (int mt = 0; mt < 4; ++mt)
#pragma unroll
        for (int nt = 0; nt < 4; ++nt) {
            acc[mt][nt][0] = 0.f; acc[mt][nt][1] = 0.f;
            acc[mt][nt][2] = 0.f; acc[mt][nt][3] = 0.f;
        }

    gl_lds16(Ag,                 &As[0][woA]);
    gl_lds16(Ag + 16 * 768,      &As[0][woA + 16 * 32]);
    gl_lds16(Wg,                 &Bs[0][woB]);
    gl_lds16(Ag + 32,            &As[1][woA]);
    gl_lds16(Ag + 32 + 16 * 768, &As[1][woA + 16 * 32]);
    gl_lds16(Wg + 32,            &Bs[1][woB]);

#pragma unroll
    for (int kt = 0; kt < 24; ++kt) {
        if (kt < 23) asm volatile("s_waitcnt vmcnt(3)" ::: "memory");
        else         asm volatile("s_waitcnt vmcnt(0)" ::: "memory");
        __builtin_amdgcn_s_barrier();
        asm volatile("" ::: "memory");

        if (kt < 22) {
            const int nb = (kt + 2) % 3;
            const int ko = (kt + 2) * 32;
            gl_lds16(Ag + ko,            &As[nb][woA]);
            gl_lds16(Ag + ko + 16 * 768, &As[nb][woA + 16 * 32]);
            gl_lds16(Wg + ko,            &Bs[nb][woB]);
        }

        const unsigned short* Ab = As[kt % 3];
        const unsigned short* Bb = Bs[kt % 3];
        s8v a[4], b[4];
#pragma unroll
        for (int mt = 0; mt < 4; ++mt)
            a[mt] = *(const s8v*)&Ab[(mw * 64 + mt * 16 + col16) * 32 + quad * 8];
#pragma unroll
        for (int nt = 0; nt < 4; ++nt)
            b[nt] = *(const s8v*)&Bb[(nw * 64 + nt * 16 + col16) * 32 + quad * 8];
#pragma unroll
        for (int mt = 0; mt < 4; ++mt)
#pragma unroll
            for (int nt = 0; nt < 4; ++nt)
                acc[mt][nt] = __builtin_amdgcn_mfma_f32_16x16x32_bf16(
                    a[mt], b[nt], acc[mt][nt], 0, 0, 0);
    }

    const int m0 = br * 256 + mw * 64 + quad * 4;
#pragma unroll
    for (int nt = 0; nt < 4; ++nt) {
        int c    = bc * 128 + nw * 64 + nt * 16 + col16;
        float bv = bias[c];
#pragma unroll
        for (int mt = 0; mt < 4; ++mt) {
#pragma unroll
            for (int i = 0; i < 4; ++i) {
                int m = m0 + mt * 16 + i;
                Out[(size_t)m * 768 + c] = acc[mt][nt][i] + bv;
            }
        }
    }
}

// ---------------------------------------------------------------------------
// Bias-table precompute via MFMA (unchanged).
// ---------------------------------------------------------------------------
__global__ __launch_bounds__(256) void bias_prep_mfma(
    const unsigned short* __restrict__ Q, const float* __restrict__ Rh,
    const float* __restrict__ Rw, unsigned short* __restrict__ qhb,
    unsigned short* __restrict__ qwb)
{
    __shared__ __align__(16) char smem[36864];
    unsigned short (*Qs)[72]  = (unsigned short (*)[72])smem;
    unsigned short (*Rs)[72]  = (unsigned short (*)[72])(smem + 18432);
    unsigned short (*Wsm)[72] = (unsigned short (*)[72])(smem + 27648);
    float (*G)[66]            = (float (*)[66])smem;

    const int t    = threadIdx.x;
    const int tc8  = blockIdx.x;   // 0..7 : 128-token chunk
    const int bh   = blockIdx.y;   // 0..95
    const int tok0 = tc8 << 7;

    for (int id = t; id < 1024; id += 256) {
        int row = id >> 3, g8 = (id & 7) << 3;
        *(uint4*)&Qs[row][g8] =
            *(const uint4*)(Q + ((size_t)bh * 1024 + tok0 + row) * 64 + g8);
    }
    for (int id = t; id < 512; id += 256) {
        int row = id >> 3, g8 = (id & 7) << 3;
        unsigned short* dh = &Rs[row][g8];
        unsigned short* dw = &Wsm[row][g8];
        if (row < 63) {
            const float* sh = Rh + row * 64 + g8;
            const float* sw = Rw + row * 64 + g8;
            float4 a = *(const float4*)sh; float4 b = *(const float4*)(sh + 4);
            float4 c = *(const float4*)sw; float4 d = *(const float4*)(sw + 4);
            dh[0] = f2bf(a.x); dh[1] = f2bf(a.y); dh[2] = f2bf(a.z); dh[3] = f2bf(a.w);
            dh[4] = f2bf(b.x); dh[5] = f2bf(b.y); dh[6] = f2bf(b.z); dh[7] = f2bf(b.w);
            dw[0] = f2bf(c.x); dw[1] = f2bf(c.y); dw[2] = f2bf(c.z); dw[3] = f2bf(c.w);
            dw[4] = f2bf(d.x); dw[5] = f2bf(d.y); dw[6] = f2bf(d.z); dw[7] = f2bf(d.w);
        } else {
#pragma unroll
            for (int j = 0; j < 8; ++j) { dh[j] = 0; dw[j] = 0; }
        }
    }
    __syncthreads();

    const int wv    = t >> 6;
    const int lane  = t & 63;
    const int col16 = lane & 15;
    const int quad  = lane >> 4;
    const int r0    = wv << 5;

    s8v qa[2][2], rb[4][2], wb[4][2];
#pragma unroll
    for (int mt = 0; mt < 2; ++mt)
#pragma unroll
        for (int kc = 0; kc < 2; ++kc)
            qa[mt][kc] = *(const s8v*)&Qs[r0 + mt * 16 + col16][kc * 32 + quad * 8];
#pragma unroll
    for (int nt = 0; nt < 4; ++nt)
#pragma unroll
        for (int kc = 0; kc < 2; ++kc) {
            rb[nt][kc] = *(const s8v*)&Rs[nt * 16 + col16][kc * 32 + quad * 8];
            wb[nt][kc] = *(const s8v*)&Wsm[nt * 16 + col16][kc * 32 + quad * 8];
        }

    f4v ah[2][4], aw[2][4];
#pragma unroll
    for (int mt = 0; mt < 2; ++mt)
#pragma unroll
        for (int nt = 0; nt < 4; ++nt) {
            f4v z; z[0] = 0.f; z[1] = 0.f; z[2] = 0.f; z[3] = 0.f;
            ah[mt][nt] = z; aw[mt][nt] = z;
        }
#pragma unroll
    for (int mt = 0; mt < 2; ++mt)
#pragma unroll
        for (int nt = 0; nt < 4; ++nt) {
            ah[mt][nt] = __builtin_amdgcn_mfma_f32_16x16x32_bf16(qa[mt][0], rb[nt][0], ah[mt][nt], 0, 0, 0);
            ah[mt][nt] = __builtin_amdgcn_mfma_f32_16x16x32_bf16(qa[mt][1], rb[nt][1], ah[mt][nt], 0, 0, 0);
            aw[mt][nt] = __builtin_amdgcn_mfma_f32_16x16x32_bf16(qa[mt][0], wb[nt][0], aw[mt][nt], 0, 0, 0);
            aw[mt][nt] = __builtin_amdgcn_mfma_f32_16x16x32_bf16(qa[mt][1], wb[nt][1], aw[mt][nt], 0, 0, 0);
        }
    __syncthreads();

    // ---- G_h ----
#pragma unroll
    for (int mt = 0; mt < 2; ++mt)
#pragma unroll
        for (int nt = 0; nt < 4; ++nt)
#pragma unroll
            for (int i = 0; i < 4; ++i)
                G[r0 + mt * 16 + quad * 4 + i][nt * 16 + col16] = ah[mt][nt][i];
    __syncthreads();
    for (int id = t; id < 2048; id += 256) {
        int tok = id >> 4, c2 = (id & 15) << 1;
        int i_img = (tc8 << 2) + (tok >> 5);
        float g0 = G[tok][i_img - c2 + 31];
        float g1 = G[tok][i_img - c2 + 30];
        unsigned pk = (unsigned)f2bf(g0) | ((unsigned)f2bf(g1) << 16);
        *(unsigned*)&qhb[(((size_t)bh << 10) + tok0 + tok) * 32 + c2] = pk;
    }
    __syncthreads();

    // ---- G_w ----
#pragma unroll
    for (int mt = 0; mt < 2; ++mt)
#pragma unroll
        for (int nt = 0; nt < 4; ++nt)
#pragma unroll
            for (int i = 0; i < 4; ++i)
                G[r0 + mt * 16 + quad * 4 + i][nt * 16 + col16] = aw[mt][nt][i];
    __syncthreads();
    for (int id = t; id < 2048; id += 256) {
        int tok = id >> 4, c2 = (id & 15) << 1;
        int j = tok & 31;
        float g0 = G[tok][j - c2 + 31];
        float g1 = G[tok][j - c2 + 30];
        unsigned pk = (unsigned)f2bf(g0) | ((unsigned)f2bf(g1) << 16);
        *(unsigned*)&qwb[(((size_t)bh << 10) + tok0 + tok) * 32 + c2] = pk;
    }
}

// ---------------------------------------------------------------------------
// R21 attention (unchanged — verified 206.6 best): q-tile 128/block, 2
// q-groups/wave sharing one set of K/V LDS reads; swizzled Ks/Vs; swapped
// QK^T; P in regs; 3 blocks/CU.
// ---------------------------------------------------------------------------
__global__ __launch_bounds__(256, 3) void attn_mfma(
    const unsigned short* __restrict__ Q, const unsigned short* __restrict__ K,
    const unsigned short* __restrict__ Vt,
    const unsigned short* __restrict__ qhb, const unsigned short* __restrict__ qwb,
    unsigned short* __restrict__ Out)
{
    const int t  = threadIdx.x;
    const int id  = blockIdx.x;           // 0..767
    const int xcd = id & 7;
    const int wq  = id >> 3;              // 0..95
    const int bh  = xcd * 12 + (wq % 12);
    const int qt  = wq / 12;              // 0..7
    const int b   = bh / 12;
    const int h   = bh - b * 12;
    const int q0  = qt << 7;              // 128-row q tile

    __shared__ __align__(16) unsigned short Ks[64 * 64];
    __shared__ __align__(16) unsigned short Vs[64 * 64];
    __shared__ float qh_s[128][33];

    const unsigned short* Kp = K  + (size_t)bh * 65536;
    const unsigned short* Vp = Vt + (size_t)bh * 65536;

    {
        const unsigned* qhp = (const unsigned*)(qhb + ((size_t)bh * 1024 + q0) * 32);
        for (int i2 = t; i2 < 2048; i2 += 256) {
            int row = i2 >> 4, c2 = (i2 & 15) << 1;
            unsigned ph = qhp[i2];
            qh_s[row][c2]     = bf2f((unsigned short)(ph & 0xffff)) - EOFF;
            qh_s[row][c2 + 1] = bf2f((unsigned short)(ph >> 16))    - EOFF;
        }
    }

    const int wv = t >> 6;
    const int lane = t & 63;
    const int c  = lane & 15;
    const int qd = lane >> 4;

    // two q-groups per wave: rows q0 + wv*32 + qg*16 + c
    s8v qfA0, qfA1, qfB0, qfB1;
    float uwA[8], uwB[8];
    {
        const size_t rowA = (size_t)bh * 1024 + q0 + (wv << 5) + c;
        const unsigned short* qpA = Q + rowA * 64 + qd * 8;
        qfA0 = *(const s8v*)qpA;
        qfA1 = *(const s8v*)(qpA + 32);
        s8v w8A = *(const s8v*)(qwb + rowA * 32 + qd * 8);
        const size_t rowB = rowA + 16;
        const unsigned short* qpB = Q + rowB * 64 + qd * 8;
        qfB0 = *(const s8v*)qpB;
        qfB1 = *(const s8v*)(qpB + 32);
        s8v w8B = *(const s8v*)(qwb + rowB * 32 + qd * 8);
#pragma unroll
        for (int j = 0; j < 8; ++j) { uwA[j] = bf2f((unsigned short)w8A[j]);
                                      uwB[j] = bf2f((unsigned short)w8B[j]); }
    }

    // swizzled LDS addressing: addr(row, col8) = row*64 + ((col8^(row&7))<<3)
    const int xlo = (qd     ^ (c & 7)) << 3;
    const int xhi = ((qd+4) ^ (c & 7)) << 3;

    const int e0 = t * 8, e1 = t * 8 + 2048;
    const int g0 = e0 >> 6, g1 = e1 >> 6;
    const int c8 = t & 7;
    const int s0 = c8 << 3;
    const int L0 = (g0 & 32) | ((g0 & 4) << 2) | ((g0 & 24) >> 1) | (g0 & 3);
    const int L1 = (g1 & 32) | ((g1 & 4) << 2) | ((g1 & 24) >> 1) | (g1 & 3);
    const int kw0 = L0 * 64 + ((c8 ^ (L0 & 7)) << 3);
    const int kw1 = L1 * 64 + ((c8 ^ (L1 & 7)) << 3);
    const int vw0 = g0 * 64 + ((c8 ^ (g0 & 7)) << 3);
    const int vw1 = g1 * 64 + ((c8 ^ (g1 & 7)) << 3);
    {
        uint4 pk0 = *(const uint4*)(Kp + e0);
        uint4 pk1 = *(const uint4*)(Kp + e1);
        uint4 pv0 = *(const uint4*)(Vp + (size_t)g0 * 1024 + s0);
        uint4 pv1 = *(const uint4*)(Vp + (size_t)g1 * 1024 + s0);
        *(uint4*)&Ks[kw0] = pk0;
        *(uint4*)&Ks[kw1] = pk1;
        *(uint4*)&Vs[vw0] = pv0;
        *(uint4*)&Vs[vw1] = pv1;
    }
    __syncthreads();

    f4v o[2][4];
#pragma unroll
    for (int qg = 0; qg < 2; ++qg)
#pragma unroll
        for (int dt = 0; dt < 4; ++dt) {
            o[qg][dt][0] = 0.f; o[qg][dt][1] = 0.f;
            o[qg][dt][2] = 0.f; o[qg][dt][3] = 0.f;
        }
    float lp[2] = {0.f, 0.f};

    for (int kt = 0; kt < 16; ++kt) {
        uint4 pk0, pk1, pv0, pv1;
        if (kt < 15) {
            const int k0n = (kt + 1) << 6;
            pk0 = *(const uint4*)(Kp + (size_t)k0n * 64 + e0);
            pk1 = *(const uint4*)(Kp + (size_t)k0n * 64 + e1);
            pv0 = *(const uint4*)(Vp + (size_t)g0 * 1024 + k0n + s0);
            pv1 = *(const uint4*)(Vp + (size_t)g1 * 1024 + k0n + s0);
        }

        // K frags read ONCE, used by both q-groups
        s8v klo[4], khi[4];
#pragma unroll
        for (int T = 0; T < 4; ++T) {
            klo[T] = *(const s8v*)&Ks[(T * 16 + c) * 64 + xlo];
            khi[T] = *(const s8v*)&Ks[(T * 16 + c) * 64 + xhi];
        }

        s8v pa[2][2];
#pragma unroll
        for (int qg = 0; qg < 2; ++qg) {
            const s8v qf0 = qg ? qfB0 : qfA0;
            const s8v qf1 = qg ? qfB1 : qfA1;
            const float* uw = qg ? uwB : uwA;
            const int qrow = (wv << 5) + qg * 16 + c;

            f4v sc[4];
#pragma unroll
            for (int T = 0; T < 4; ++T) {
                f4v z; z[0] = 0.f; z[1] = 0.f; z[2] = 0.f; z[3] = 0.f;
                z = __builtin_amdgcn_mfma_f32_16x16x32_bf16(klo[T], qf0, z, 0, 0, 0);
                z = __builtin_amdgcn_mfma_f32_16x16x32_bf16(khi[T], qf1, z, 0, 0, 0);
                sc[T] = z;
            }

            const float qhv0 = qh_s[qrow][(kt << 1)];
            const float qhv1 = qh_s[qrow][(kt << 1) + 1];

#pragma unroll
            for (int j = 0; j < 4; ++j) {
                float pe = __builtin_amdgcn_exp2f(sc[0][j] + qhv0 + uw[j]);
                lp[qg] += pe; pa[qg][0][j] = (short)f2bf(pe);
            }
#pragma unroll
            for (int j = 0; j < 4; ++j) {
                float pe = __builtin_amdgcn_exp2f(sc[1][j] + qhv0 + uw[4 + j]);
                lp[qg] += pe; pa[qg][0][4 + j] = (short)f2bf(pe);
            }
#pragma unroll
            for (int j = 0; j < 4; ++j) {
                float pe = __builtin_amdgcn_exp2f(sc[2][j] + qhv1 + uw[j]);
                lp[qg] += pe; pa[qg][1][j] = (short)f2bf(pe);
            }
#pragma unroll
            for (int j = 0; j < 4; ++j) {
                float pe = __builtin_amdgcn_exp2f(sc[3][j] + qhv1 + uw[4 + j]);
                lp[qg] += pe; pa[qg][1][4 + j] = (short)f2bf(pe);
            }
        }

        // V frags read ONCE, used by both q-groups
#pragma unroll
        for (int dt = 0; dt < 4; ++dt) {
            s8v vlo = *(const s8v*)&Vs[(dt * 16 + c) * 64 + xlo];
            s8v vhi = *(const s8v*)&Vs[(dt * 16 + c) * 64 + xhi];
#pragma unroll
            for (int qg = 0; qg < 2; ++qg) {
                o[qg][dt] = __builtin_amdgcn_mfma_f32_16x16x32_bf16(pa[qg][0], vlo, o[qg][dt], 0, 0, 0);
                o[qg][dt] = __builtin_amdgcn_mfma_f32_16x16x32_bf16(pa[qg][1], vhi, o[qg][dt], 0, 0, 0);
            }
        }

        __syncthreads();
        if (kt < 15) {
            *(uint4*)&Ks[kw0] = pk0;
            *(uint4*)&Ks[kw1] = pk1;
            *(uint4*)&Vs[vw0] = pv0;
            *(uint4*)&Vs[vw1] = pv1;
        }
        __syncthreads();
    }

#pragma unroll
    for (int qg = 0; qg < 2; ++qg) {
        lp[qg] += __shfl_xor(lp[qg], 16);
        lp[qg] += __shfl_xor(lp[qg], 32);
#pragma unroll
        for (int i = 0; i < 4; ++i) {
            float inv = 1.f / __shfl(lp[qg], (qd << 2) + i);
            int qr = q0 + (wv << 5) + qg * 16 + (qd << 2) + i;
            unsigned short* dst = Out + ((size_t)b * 1024 + qr) * 768 + h * 64;
#pragma unroll
            for (int dt = 0; dt < 4; ++dt)
                dst[dt * 16 + c] = f2bf(o[qg][dt][i] * inv);
        }
    }
}

extern "C" void kernel_launch(void* const* d_in, const int* in_sizes, int n_in,
                              void* d_out, int out_size, void* d_ws, size_t ws_size,
                              hipStream_t stream) {
    const float* x      = (const float*)d_in[0];
    const float* qkv_w  = (const float*)d_in[1];
    const float* qkv_b  = (const float*)d_in[2];
    const float* proj_w = (const float*)d_in[3];
    const float* proj_b = (const float*)d_in[4];
    const float* rel_h  = (const float*)d_in[5];
    const float* rel_w  = (const float*)d_in[6];
    float* out = (float*)d_out;

    char* ws = (char*)d_ws;
    unsigned short* qbuf  = (unsigned short*)(ws);             // bf16 [96][1024][64] 12582912
    unsigned short* kbuf  = (unsigned short*)(ws + 12582912);  // bf16 [96][1024][64] 12582912
    unsigned short* vtbuf = (unsigned short*)(ws + 25165824);  // bf16 [96][64][1024] 12582912
    unsigned short* xab   = (unsigned short*)(ws + 37748736);  // bf16 x / attn-out   12582912
    unsigned short* wqb   = (unsigned short*)(ws + 50331648);  // bf16 qkv_w          3538944
    unsigned short* wpb   = (unsigned short*)(ws + 53870592);  // bf16 proj_w         1179648
    unsigned short* qhb   = (unsigned short*)(ws + 55050240);  // bf16 [96][1024][32] 6291456
    unsigned short* qwb   = (unsigned short*)(ws + 61341696);  // bf16 [96][1024][32] 6291456

    to_bf16_all<<<4224, 256, 0, stream>>>(x, qkv_w, proj_w, xab, wqb, wpb);
    qkv_gemm_mfma<<<576, 512, 0, stream>>>(xab, wqb, qkv_b, qbuf, kbuf, vtbuf);
    bias_prep_mfma<<<dim3(8, 96), 256, 0, stream>>>(qbuf, rel_h, rel_w, qhb, qwb);
    attn_mfma<<<768, 256, 0, stream>>>(qbuf, kbuf, vtbuf, qhb, qwb, xab);
    proj_gemm_mfma<<<192, 512, 0, stream>>>(xab, wpb, proj_b, out);
}